// Round 14
// baseline (464.636 us; speedup 1.0000x reference)
//
#include <hip/hip_runtime.h>
#include <cstdint>
#include <cstddef>

#define NEG_SLOPE 0.2f
#define NSPREAD 32

__device__ __forceinline__ float lrelu(float v) { return v >= 0.f ? v : NEG_SLOPE * v; }

// bf16 pack/unpack (round-to-nearest-even)
__device__ __forceinline__ unsigned short f2bf(float x) {
    union { float f; uint32_t u; } v; v.f = x;
    uint32_t r = v.u + 0x7FFFu + ((v.u >> 16) & 1u);
    return (unsigned short)(r >> 16);
}
__device__ __forceinline__ float bf2f_lo(uint32_t u) {
    union { uint32_t u; float f; } v; v.u = u << 16;
    return v.f;
}
__device__ __forceinline__ float bf2f_hi(uint32_t u) {
    union { uint32_t u; float f; } v; v.u = u & 0xFFFF0000u;
    return v.f;
}

// spread-copy index: derived from e only, so degpos and scatter always agree
__device__ __forceinline__ int spreadk(int e) { return (e >> 8) & (NSPREAD - 1); }

#define L1_NODES 64

// ==================== fused: degree count (blocks first)  ∥  layer-1 linear/scores ====
// blocks [0, 3*nbE): degpos — NSPREAD-way-spread degree histogram + slot epos
// blocks [3*nbE, 3*nbE+nL1): linear1 tiles (384 thr = one W column each, 64-node tile)
__global__ __launch_bounds__(384) void k_lin1_deg(
        const float* __restrict__ X,
        const float* __restrict__ W1, const float* __restrict__ W2,
        const float* __restrict__ W3,
        const float* __restrict__ as1, const float* __restrict__ ad1,
        const float* __restrict__ as2, const float* __restrict__ ad2,
        const float* __restrict__ as3, const float* __restrict__ ad3,
        unsigned short* __restrict__ h_bf,
        float* __restrict__ s_src, float* __restrict__ s_dst,
        const int* __restrict__ A1, const int* __restrict__ A2,
        const int* __restrict__ A3,
        int* __restrict__ degS, unsigned short* __restrict__ epos,
        int nL1, int nbE, int E, int N) {
    int t = threadIdx.x;
    if (blockIdx.x < 3 * (unsigned)nbE) {
        // ---- degpos path ----
        int b = blockIdx.x;
        int r = b / nbE;
        int e = (b - r * nbE) * 384 + t;
        if (e < E) {
            const int* A = (r == 0) ? A1 : (r == 1) ? A2 : A3;
            int dst = A[E + e];
            epos[(size_t)r * E + e] = (unsigned short)atomicAdd(
                &degS[(size_t)(r * NSPREAD + spreadk(e)) * N + dst], 1);
        }
        return;
    }
    // ---- linear1 path ----
    __shared__ float Xs[L1_NODES][64];
    int n0 = (blockIdx.x - 3 * nbE) * L1_NODES;
    {
        const float4* X4 = reinterpret_cast<const float4*>(X);
        float4* Xs4 = reinterpret_cast<float4*>(&Xs[0][0]);
        for (int i = t; i < L1_NODES * 16; i += 384) {
            int nl = i >> 4;
            float4 xv = make_float4(0.f, 0.f, 0.f, 0.f);
            if (n0 + nl < N) xv = X4[(size_t)(n0 + nl) * 16 + (i & 15)];
            Xs4[i] = xv;
        }
    }
    int r = t >> 7, col = t & 127, head = (t >> 4) & 7, c = t & 15;
    const float* Wp = ((r == 0) ? W1 : (r == 1) ? W2 : W3) + col;
    float Wc[64];
    #pragma unroll
    for (int k = 0; k < 64; ++k) Wc[k] = Wp[(size_t)k * 128];
    float as_v = ((r == 0) ? as1 : (r == 1) ? as2 : as3)[head * 16 + c];
    float ad_v = ((r == 0) ? ad1 : (r == 1) ? ad2 : ad3)[head * 16 + c];
    __syncthreads();
    int nmax = min(L1_NODES, N - n0);
    int rh = (r << 3) + head;
    for (int n = 0; n < nmax; ++n) {
        const float4* xr = reinterpret_cast<const float4*>(&Xs[n][0]);
        float a0 = 0.f, a1 = 0.f, a2 = 0.f, a3 = 0.f;
        #pragma unroll
        for (int k4 = 0; k4 < 16; ++k4) {
            float4 xv = xr[k4];
            a0 = fmaf(xv.x, Wc[k4 * 4 + 0], a0);
            a1 = fmaf(xv.y, Wc[k4 * 4 + 1], a1);
            a2 = fmaf(xv.z, Wc[k4 * 4 + 2], a2);
            a3 = fmaf(xv.w, Wc[k4 * 4 + 3], a3);
        }
        float acc = (a0 + a1) + (a2 + a3);
        h_bf[(size_t)(n0 + n) * 384 + t] = f2bf(acc);
        float ss = acc * as_v, sd = acc * ad_v;
        ss += __shfl_xor(ss, 1); ss += __shfl_xor(ss, 2);
        ss += __shfl_xor(ss, 4); ss += __shfl_xor(ss, 8);
        sd += __shfl_xor(sd, 1); sd += __shfl_xor(sd, 2);
        sd += __shfl_xor(sd, 4); sd += __shfl_xor(sd, 8);
        if (c == 0) {
            s_src[(size_t)(n0 + n) * 24 + rh] = ss;
            s_dst[(size_t)(n0 + n) * 24 + rh] = sd;
        }
    }
}

// ==================== CSR scans ====================
__global__ void k_scanA2(const int* __restrict__ degS, int* __restrict__ deg,
                         int* __restrict__ startk, int* __restrict__ start,
                         int* __restrict__ bsum, int total, int N) {
    __shared__ int tmp[256];
    int t = threadIdx.x;
    int base = blockIdx.x * 1024 + t * 4;
    int v[4]; int s = 0;
    #pragma unroll
    for (int m = 0; m < 4; ++m) {
        int g = base + m;
        int sumS = 0;
        if (g < total) {
            int r = g / N;
            int n = g - r * N;
            #pragma unroll
            for (int k = 0; k < NSPREAD; ++k) {
                size_t idx = (size_t)(r * NSPREAD + k) * N + n;
                int dv = degS[idx];
                startk[idx] = sumS;
                sumS += dv;
            }
            deg[g] = sumS;
        }
        v[m] = sumS; s += sumS;
    }
    tmp[t] = s; __syncthreads();
    for (int off = 1; off < 256; off <<= 1) {
        int x = (t >= off) ? tmp[t - off] : 0; __syncthreads();
        tmp[t] += x; __syncthreads();
    }
    int run = tmp[t] - s;
    #pragma unroll
    for (int m = 0; m < 4; ++m) {
        if (base + m < total) start[base + m] = run;
        run += v[m];
    }
    if (t == 255) bsum[blockIdx.x] = tmp[255];
}

__global__ void k_scanB(int* __restrict__ bsum, int nb) {
    __shared__ int tmp[256];
    int t = threadIdx.x;
    int v[4]; int s = 0;
    #pragma unroll
    for (int k = 0; k < 4; ++k) { int i = t * 4 + k; v[k] = (i < nb) ? bsum[i] : 0; s += v[k]; }
    tmp[t] = s; __syncthreads();
    for (int off = 1; off < 256; off <<= 1) {
        int x = (t >= off) ? tmp[t - off] : 0; __syncthreads();
        tmp[t] += x; __syncthreads();
    }
    int run = tmp[t] - s;
    #pragma unroll
    for (int k = 0; k < 4; ++k) {
        int i = t * 4 + k;
        if (i < nb) { int vv = v[k]; bsum[i] = run; run += vv; }
    }
}

// scan C: finalize global base; push base into the NSPREAD startk copies; zero h2
__global__ void k_scanC2(int* __restrict__ start, const int* __restrict__ bsum,
                         int* __restrict__ startk, float* __restrict__ h2,
                         int total, int N, int E) {
    int g = blockIdx.x * blockDim.x + threadIdx.x;
    if (g >= total) return;
    h2[g] = 0.f;
    int r = g / N;
    int n = g - r * N;
    int base = start[g] + bsum[g >> 10] - r * E;
    start[g] = base;
    #pragma unroll
    for (int k = 0; k < NSPREAD; ++k)
        startk[(size_t)(r * NSPREAD + k) * N + n] += base;
}

// scatter: no atomics — pos = startk[k(e)][dst] + epos
__global__ void k_scatter2(const int* __restrict__ A1, const int* __restrict__ A2,
                           const int* __restrict__ A3,
                           const int* __restrict__ startk,
                           const unsigned short* __restrict__ epos,
                           unsigned short* __restrict__ csr, int E, int N) {
    int e = blockIdx.x * blockDim.x + threadIdx.x;
    if (e >= E) return;
    int r = blockIdx.y;
    const int* A = (r == 0) ? A1 : (r == 1) ? A2 : A3;
    int src = A[e], dst = A[E + e];
    int pos = startk[(size_t)(r * NSPREAD + spreadk(e)) * N + dst] + epos[(size_t)r * E + e];
    csr[(size_t)r * E + pos] = (unsigned short)src;
}

// ==================== layer-1 aggregation + fused layer-2 linear ====================
__global__ __launch_bounds__(64) void k_agg1(
        const unsigned short* __restrict__ h_bf,
        const float* __restrict__ s_src, const float* __restrict__ s_dst,
        const int* __restrict__ deg, const int* __restrict__ start,
        const unsigned short* __restrict__ csr,
        const float* __restrict__ b1, const float* __restrict__ b2,
        const float* __restrict__ b3,
        const float* __restrict__ W12, const float* __restrict__ W22,
        const float* __restrict__ W32,
        float* __restrict__ h2, int E, int N) {
    __shared__ int sidx[64];
    __shared__ float sex[64 * 8];
    int n = blockIdx.x;
    int r = blockIdx.y;
    int j = threadIdx.x;              // uint channel-pair index 0..63
    int h = j >> 3;                   // head (16 ch = 8 uints per head)
    int rh = r * 8 + h;
    int s0 = start[(size_t)r * N + n];
    int d  = deg[(size_t)r * N + n];
    const uint32_t* hb = reinterpret_cast<const uint32_t*>(h_bf);
    int off = r * 64 + j;
    float sd = s_dst[(size_t)n * 24 + rh];
    float ex0 = __expf(lrelu(s_src[(size_t)n * 24 + rh] + sd));
    float denom = ex0;
    uint32_t hv0 = hb[(size_t)n * 192 + off];
    float accx = ex0 * bf2f_lo(hv0);
    float accy = ex0 * bf2f_hi(hv0);
    int hA = j & 7;
    float sdA = s_dst[(size_t)n * 24 + r * 8 + hA];
    const unsigned short* cs = csr + (size_t)r * E + s0;
    for (int c0 = 0; c0 < d; c0 += 64) {
        int dc = min(64, d - c0);
        if (j < dc) sidx[j] = cs[c0 + j];
        __syncthreads();
        // phase A: one exp per (neighbor, head)
        for (int p = j; p < dc * 8; p += 64) {
            int i = p >> 3;
            float ssv = s_src[(size_t)sidx[i] * 24 + r * 8 + hA];
            sex[p] = __expf(lrelu(ssv + sdA));
        }
        __syncthreads();
        // phase B: gather + accumulate (one uint = 2 bf16 per thread, 256B/wave/neighbor)
        for (int i = 0; i < dc; ++i) {
            float ex = sex[i * 8 + h];
            uint32_t hv = hb[(size_t)sidx[i] * 192 + off];
            denom += ex;
            accx = fmaf(ex, bf2f_lo(hv), accx);
            accy = fmaf(ex, bf2f_hi(hv), accy);
        }
        __syncthreads();
    }
    const float* b = (r == 0) ? b1 : (r == 1) ? b2 : b3;
    float inv = 1.0f / (denom + 1e-16f);
    float ox = accx * inv + b[2 * j];
    float oy = accy * inv + b[2 * j + 1];
    ox = (ox > 0.f) ? ox : 0.f;
    oy = (oy > 0.f) ? oy : 0.f;
    // fused layer-2 linear: partial dots over this block's 128 channels
    int cbase = r * 128 + 2 * j;
    float p0 = ox * W12[cbase] + oy * W12[cbase + 1];
    float p1 = ox * W22[cbase] + oy * W22[cbase + 1];
    float p2 = ox * W32[cbase] + oy * W32[cbase + 1];
    #pragma unroll
    for (int o = 32; o > 0; o >>= 1) {
        p0 += __shfl_xor(p0, o);
        p1 += __shfl_xor(p1, o);
        p2 += __shfl_xor(p2, o);
    }
    if (j == 0) {
        atomicAdd(&h2[(size_t)n * 3 + 0], p0);
        atomicAdd(&h2[(size_t)n * 3 + 1], p1);
        atomicAdd(&h2[(size_t)n * 3 + 2], p2);
    }
}

// ==================== layer-2 aggregation + final projection ====================
__global__ __launch_bounds__(384) void k_agg2f(
        const float* __restrict__ h2,
        const int* __restrict__ deg, const int* __restrict__ start,
        const unsigned short* __restrict__ csr,
        const float* __restrict__ as1, const float* __restrict__ ad1,
        const float* __restrict__ as2, const float* __restrict__ ad2,
        const float* __restrict__ as3, const float* __restrict__ ad3,
        const float* __restrict__ b1, const float* __restrict__ b2,
        const float* __restrict__ b3,
        const float* __restrict__ ln_w, const float* __restrict__ ln_b,
        float* __restrict__ out, int E, int N) {
    __shared__ float ys[48];
    int tl = threadIdx.x;
    int pl = tl >> 3;                 // unit 0..47
    int q  = tl & 7;                  // lane in unit
    int id = blockIdx.x * 48 + pl;
    bool valid = id < 3 * N;
    int n = id / 3;
    int r = id - 3 * n;
    float denom = 0.f, acc = 0.f;
    if (valid) {
        float a_s = ((r == 0) ? as1 : (r == 1) ? as2 : as3)[0];
        float a_d = ((r == 0) ? ad1 : (r == 1) ? ad2 : ad3)[0];
        int s0 = start[(size_t)r * N + n];
        int d  = deg[(size_t)r * N + n];
        float hd = h2[id];
        float sd = a_d * hd;
        const unsigned short* cs = csr + (size_t)r * E + s0;
        for (int i = q; i < d; i += 8) {
            float hs = h2[(size_t)cs[i] * 3 + r];
            float e2 = __expf(lrelu(fmaf(a_s, hs, sd)));
            denom += e2;
            acc = fmaf(e2, hs, acc);
        }
        if (q == 0) {
            float ev = __expf(lrelu(fmaf(a_s, hd, sd)));
            denom += ev;
            acc = fmaf(ev, hd, acc);
        }
    }
    denom += __shfl_xor(denom, 1); denom += __shfl_xor(denom, 2); denom += __shfl_xor(denom, 4);
    acc   += __shfl_xor(acc, 1);   acc   += __shfl_xor(acc, 2);   acc   += __shfl_xor(acc, 4);
    if (valid && q == 0) {
        float b = ((r == 0) ? b1 : (r == 1) ? b2 : b3)[0];
        ys[pl] = (acc / (denom + 1e-16f) + b) * ln_w[r];
    }
    __syncthreads();
    if (valid && q == 0 && r == 0)
        out[n] = ys[pl] + ys[pl + 1] + ys[pl + 2] + ln_b[0];
}

extern "C" void kernel_launch(void* const* d_in, const int* in_sizes, int n_in,
                              void* d_out, int out_size, void* d_ws, size_t ws_size,
                              hipStream_t stream) {
    const float* X  = (const float*)d_in[0];
    const int*   A1 = (const int*)d_in[1];
    const int*   A2 = (const int*)d_in[2];
    const int*   A3 = (const int*)d_in[3];
    const float* W11 = (const float*)d_in[5];
    const float* as11 = (const float*)d_in[6];
    const float* ad11 = (const float*)d_in[7];
    const float* b11 = (const float*)d_in[8];
    const float* W12 = (const float*)d_in[9];
    const float* as12 = (const float*)d_in[10];
    const float* ad12 = (const float*)d_in[11];
    const float* b12 = (const float*)d_in[12];
    const float* W21 = (const float*)d_in[13];
    const float* as21 = (const float*)d_in[14];
    const float* ad21 = (const float*)d_in[15];
    const float* b21 = (const float*)d_in[16];
    const float* W22 = (const float*)d_in[17];
    const float* as22 = (const float*)d_in[18];
    const float* ad22 = (const float*)d_in[19];
    const float* b22 = (const float*)d_in[20];
    const float* W31 = (const float*)d_in[21];
    const float* as31 = (const float*)d_in[22];
    const float* ad31 = (const float*)d_in[23];
    const float* b31 = (const float*)d_in[24];
    const float* W32 = (const float*)d_in[25];
    const float* as32 = (const float*)d_in[26];
    const float* ad32 = (const float*)d_in[27];
    const float* b32 = (const float*)d_in[28];
    const float* ln_w = (const float*)d_in[29];
    const float* ln_b = (const float*)d_in[30];

    const int N = in_sizes[0] / 64;
    const int E = in_sizes[1] / 2;
    const int total = 3 * N;
    const int nbA = (total + 1023) / 1024;
    const int nL1 = (N + L1_NODES - 1) / L1_NODES;
    const int nbE = (E + 383) / 384;

    // workspace layout
    float* w = (float*)d_ws;
    float* s_src1 = w; w += (size_t)N * 24;
    float* s_dst1 = w; w += (size_t)N * 24;
    float* h2     = w; w += (size_t)N * 3;
    unsigned short* h_bf = (unsigned short*)w; w += (size_t)N * 192;  // N*384 bf16
    int* iw     = (int*)w;
    int* deg    = iw; iw += (size_t)3 * N;
    int* start  = iw; iw += (size_t)3 * N;
    int* bsum   = iw; iw += 1024;
    int* degS   = iw; iw += (size_t)3 * NSPREAD * N;
    int* startk = iw; iw += (size_t)3 * NSPREAD * N;
    unsigned short* epos = (unsigned short*)iw;
    unsigned short* csr  = epos + (size_t)3 * E;

    const int BLK = 256;

    hipMemsetAsync(degS, 0, (size_t)3 * NSPREAD * N * sizeof(int), stream);

    // ---- fused: degpos (first) ∥ linear1 ----
    k_lin1_deg<<<3 * nbE + nL1, 384, 0, stream>>>(
        X, W11, W21, W31, as11, ad11, as21, ad21, as31, ad31,
        h_bf, s_src1, s_dst1,
        A1, A2, A3, degS, epos, nL1, nbE, E, N);

    // ---- CSR scans + scatter ----
    k_scanA2<<<nbA, 256, 0, stream>>>(degS, deg, startk, start, bsum, total, N);
    k_scanB<<<1, 256, 0, stream>>>(bsum, nbA);
    k_scanC2<<<(total + BLK - 1) / BLK, BLK, 0, stream>>>(start, bsum, startk, h2, total, N, E);
    {
        dim3 grid((E + BLK - 1) / BLK, 3);
        k_scatter2<<<grid, BLK, 0, stream>>>(A1, A2, A3, startk, epos, csr, E, N);
    }

    // ---- layer-1 aggregation (+ fused layer-2 linear) ----
    {
        dim3 grid(N, 3);
        k_agg1<<<grid, 64, 0, stream>>>(h_bf, s_src1, s_dst1, deg, start, csr,
                                        b11, b21, b31, W12, W22, W32, h2, E, N);
    }

    // ---- layer-2 aggregation + final projection ----
    {
        int nb = (total + 47) / 48;
        k_agg2f<<<nb, 384, 0, stream>>>(
            h2, deg, start, csr,
            as12, ad12, as22, ad22, as32, ad32,
            b12, b22, b32, ln_w, ln_b, (float*)d_out, E, N);
    }
}

// Round 15
// 377.326 us; speedup vs baseline: 1.2314x; 1.2314x over previous
//
#include <hip/hip_runtime.h>
#include <cstdint>
#include <cstddef>

#define NEG_SLOPE 0.2f

__device__ __forceinline__ float lrelu(float v) { return v >= 0.f ? v : NEG_SLOPE * v; }

// bf16 pack/unpack (round-to-nearest-even)
__device__ __forceinline__ unsigned short f2bf(float x) {
    union { float f; uint32_t u; } v; v.f = x;
    uint32_t r = v.u + 0x7FFFu + ((v.u >> 16) & 1u);
    return (unsigned short)(r >> 16);
}
__device__ __forceinline__ float bf2f_lo(uint32_t u) {
    union { uint32_t u; float f; } v; v.u = u << 16;
    return v.f;
}
__device__ __forceinline__ float bf2f_hi(uint32_t u) {
    union { uint32_t u; float f; } v; v.u = u & 0xFFFF0000u;
    return v.f;
}

// spread-copy index: derived from e only, so degpos and scatter always agree
__device__ __forceinline__ int spreadk(int e) { return (e >> 8) & 7; }

#define L1_NODES 64

// ==================== fused: layer-1 linear/scores  ∥  degree count ====================
// blocks [0, nL1): linear1 tiles (384 thr = one W column each, 64-node tile)
// blocks [nL1, nL1+3*nbE): degpos — 8-way-spread degree histogram + slot epos
__global__ __launch_bounds__(384) void k_lin1_deg(
        const float* __restrict__ X,
        const float* __restrict__ W1, const float* __restrict__ W2,
        const float* __restrict__ W3,
        const float* __restrict__ as1, const float* __restrict__ ad1,
        const float* __restrict__ as2, const float* __restrict__ ad2,
        const float* __restrict__ as3, const float* __restrict__ ad3,
        unsigned short* __restrict__ h_bf,
        float* __restrict__ s_src, float* __restrict__ s_dst,
        const int* __restrict__ A1, const int* __restrict__ A2,
        const int* __restrict__ A3,
        int* __restrict__ deg8, unsigned short* __restrict__ epos,
        int nL1, int nbE, int E, int N) {
    int t = threadIdx.x;
    if (blockIdx.x >= nL1) {
        // ---- degpos path ----
        int b = blockIdx.x - nL1;
        int r = b / nbE;
        int e = (b - r * nbE) * 384 + t;
        if (e < E) {
            const int* A = (r == 0) ? A1 : (r == 1) ? A2 : A3;
            int dst = A[E + e];
            epos[(size_t)r * E + e] =
                (unsigned short)atomicAdd(&deg8[(size_t)((r << 3) + spreadk(e)) * N + dst], 1);
        }
        return;
    }
    // ---- linear1 path ----
    __shared__ float Xs[L1_NODES][64];
    int n0 = blockIdx.x * L1_NODES;
    {
        const float4* X4 = reinterpret_cast<const float4*>(X);
        float4* Xs4 = reinterpret_cast<float4*>(&Xs[0][0]);
        for (int i = t; i < L1_NODES * 16; i += 384) {
            int nl = i >> 4;
            float4 xv = make_float4(0.f, 0.f, 0.f, 0.f);
            if (n0 + nl < N) xv = X4[(size_t)(n0 + nl) * 16 + (i & 15)];
            Xs4[i] = xv;
        }
    }
    int r = t >> 7, col = t & 127, head = (t >> 4) & 7, c = t & 15;
    const float* Wp = ((r == 0) ? W1 : (r == 1) ? W2 : W3) + col;
    float Wc[64];
    #pragma unroll
    for (int k = 0; k < 64; ++k) Wc[k] = Wp[(size_t)k * 128];
    float as_v = ((r == 0) ? as1 : (r == 1) ? as2 : as3)[head * 16 + c];
    float ad_v = ((r == 0) ? ad1 : (r == 1) ? ad2 : ad3)[head * 16 + c];
    __syncthreads();
    int nmax = min(L1_NODES, N - n0);
    int rh = (r << 3) + head;
    for (int n = 0; n < nmax; ++n) {
        const float4* xr = reinterpret_cast<const float4*>(&Xs[n][0]);
        float a0 = 0.f, a1 = 0.f, a2 = 0.f, a3 = 0.f;
        #pragma unroll
        for (int k4 = 0; k4 < 16; ++k4) {
            float4 xv = xr[k4];
            a0 = fmaf(xv.x, Wc[k4 * 4 + 0], a0);
            a1 = fmaf(xv.y, Wc[k4 * 4 + 1], a1);
            a2 = fmaf(xv.z, Wc[k4 * 4 + 2], a2);
            a3 = fmaf(xv.w, Wc[k4 * 4 + 3], a3);
        }
        float acc = (a0 + a1) + (a2 + a3);
        h_bf[(size_t)(n0 + n) * 384 + t] = f2bf(acc);
        float ss = acc * as_v, sd = acc * ad_v;
        ss += __shfl_xor(ss, 1); ss += __shfl_xor(ss, 2);
        ss += __shfl_xor(ss, 4); ss += __shfl_xor(ss, 8);
        sd += __shfl_xor(sd, 1); sd += __shfl_xor(sd, 2);
        sd += __shfl_xor(sd, 4); sd += __shfl_xor(sd, 8);
        if (c == 0) {
            s_src[(size_t)(n0 + n) * 24 + rh] = ss;
            s_dst[(size_t)(n0 + n) * 24 + rh] = sd;
        }
    }
}

// ==================== CSR scans ====================
__global__ void k_scanA2(const int* __restrict__ deg8, int* __restrict__ deg,
                         int* __restrict__ startk, int* __restrict__ start,
                         int* __restrict__ bsum, int total, int N) {
    __shared__ int tmp[256];
    int t = threadIdx.x;
    int base = blockIdx.x * 1024 + t * 4;
    int v[4]; int s = 0;
    #pragma unroll
    for (int m = 0; m < 4; ++m) {
        int g = base + m;
        int sum8 = 0;
        if (g < total) {
            int r = g / N;
            int n = g - r * N;
            #pragma unroll
            for (int k = 0; k < 8; ++k) {
                size_t idx = (size_t)((r << 3) + k) * N + n;
                int dv = deg8[idx];
                startk[idx] = sum8;
                sum8 += dv;
            }
            deg[g] = sum8;
        }
        v[m] = sum8; s += sum8;
    }
    tmp[t] = s; __syncthreads();
    for (int off = 1; off < 256; off <<= 1) {
        int x = (t >= off) ? tmp[t - off] : 0; __syncthreads();
        tmp[t] += x; __syncthreads();
    }
    int run = tmp[t] - s;
    #pragma unroll
    for (int m = 0; m < 4; ++m) {
        if (base + m < total) start[base + m] = run;
        run += v[m];
    }
    if (t == 255) bsum[blockIdx.x] = tmp[255];
}

__global__ void k_scanB(int* __restrict__ bsum, int nb) {
    __shared__ int tmp[256];
    int t = threadIdx.x;
    int v[4]; int s = 0;
    #pragma unroll
    for (int k = 0; k < 4; ++k) { int i = t * 4 + k; v[k] = (i < nb) ? bsum[i] : 0; s += v[k]; }
    tmp[t] = s; __syncthreads();
    for (int off = 1; off < 256; off <<= 1) {
        int x = (t >= off) ? tmp[t - off] : 0; __syncthreads();
        tmp[t] += x; __syncthreads();
    }
    int run = tmp[t] - s;
    #pragma unroll
    for (int k = 0; k < 4; ++k) {
        int i = t * 4 + k;
        if (i < nb) { int vv = v[k]; bsum[i] = run; run += vv; }
    }
}

// scan C: finalize global base; push base into the 8 startk copies; zero h2
__global__ void k_scanC2(int* __restrict__ start, const int* __restrict__ bsum,
                         int* __restrict__ startk, float* __restrict__ h2,
                         int total, int N, int E) {
    int g = blockIdx.x * blockDim.x + threadIdx.x;
    if (g >= total) return;
    h2[g] = 0.f;
    int r = g / N;
    int n = g - r * N;
    int base = start[g] + bsum[g >> 10] - r * E;
    start[g] = base;
    #pragma unroll
    for (int k = 0; k < 8; ++k)
        startk[(size_t)((r << 3) + k) * N + n] += base;
}

// scatter: no atomics — pos = startk[k(e)][dst] + epos
__global__ void k_scatter2(const int* __restrict__ A1, const int* __restrict__ A2,
                           const int* __restrict__ A3,
                           const int* __restrict__ startk,
                           const unsigned short* __restrict__ epos,
                           unsigned short* __restrict__ csr, int E, int N) {
    int e = blockIdx.x * blockDim.x + threadIdx.x;
    if (e >= E) return;
    int r = blockIdx.y;
    const int* A = (r == 0) ? A1 : (r == 1) ? A2 : A3;
    int src = A[e], dst = A[E + e];
    int pos = startk[(size_t)((r << 3) + spreadk(e)) * N + dst] + epos[(size_t)r * E + e];
    csr[(size_t)r * E + pos] = (unsigned short)src;
}

// ==================== layer-1 aggregation + fused layer-2 linear ====================
__global__ __launch_bounds__(64) void k_agg1(
        const unsigned short* __restrict__ h_bf,
        const float* __restrict__ s_src, const float* __restrict__ s_dst,
        const int* __restrict__ deg, const int* __restrict__ start,
        const unsigned short* __restrict__ csr,
        const float* __restrict__ b1, const float* __restrict__ b2,
        const float* __restrict__ b3,
        const float* __restrict__ W12, const float* __restrict__ W22,
        const float* __restrict__ W32,
        float* __restrict__ h2, int E, int N) {
    __shared__ int sidx[64];
    __shared__ float sex[64 * 8];
    int n = blockIdx.x;
    int r = blockIdx.y;
    int j = threadIdx.x;              // uint channel-pair index 0..63
    int h = j >> 3;                   // head (16 ch = 8 uints per head)
    int rh = r * 8 + h;
    int s0 = start[(size_t)r * N + n];
    int d  = deg[(size_t)r * N + n];
    const uint32_t* hb = reinterpret_cast<const uint32_t*>(h_bf);
    int off = r * 64 + j;
    float sd = s_dst[(size_t)n * 24 + rh];
    float ex0 = __expf(lrelu(s_src[(size_t)n * 24 + rh] + sd));
    float denom = ex0;
    uint32_t hv0 = hb[(size_t)n * 192 + off];
    float accx = ex0 * bf2f_lo(hv0);
    float accy = ex0 * bf2f_hi(hv0);
    int hA = j & 7;
    float sdA = s_dst[(size_t)n * 24 + r * 8 + hA];
    const unsigned short* cs = csr + (size_t)r * E + s0;
    for (int c0 = 0; c0 < d; c0 += 64) {
        int dc = min(64, d - c0);
        if (j < dc) sidx[j] = cs[c0 + j];
        __syncthreads();
        // phase A: one exp per (neighbor, head)
        for (int p = j; p < dc * 8; p += 64) {
            int i = p >> 3;
            float ssv = s_src[(size_t)sidx[i] * 24 + r * 8 + hA];
            sex[p] = __expf(lrelu(ssv + sdA));
        }
        __syncthreads();
        // phase B: gather + accumulate (one uint = 2 bf16 per thread, 256B/wave/neighbor)
        for (int i = 0; i < dc; ++i) {
            float ex = sex[i * 8 + h];
            uint32_t hv = hb[(size_t)sidx[i] * 192 + off];
            denom += ex;
            accx = fmaf(ex, bf2f_lo(hv), accx);
            accy = fmaf(ex, bf2f_hi(hv), accy);
        }
        __syncthreads();
    }
    const float* b = (r == 0) ? b1 : (r == 1) ? b2 : b3;
    float inv = 1.0f / (denom + 1e-16f);
    float ox = accx * inv + b[2 * j];
    float oy = accy * inv + b[2 * j + 1];
    ox = (ox > 0.f) ? ox : 0.f;
    oy = (oy > 0.f) ? oy : 0.f;
    // fused layer-2 linear: partial dots over this block's 128 channels
    int cbase = r * 128 + 2 * j;
    float p0 = ox * W12[cbase] + oy * W12[cbase + 1];
    float p1 = ox * W22[cbase] + oy * W22[cbase + 1];
    float p2 = ox * W32[cbase] + oy * W32[cbase + 1];
    #pragma unroll
    for (int o = 32; o > 0; o >>= 1) {
        p0 += __shfl_xor(p0, o);
        p1 += __shfl_xor(p1, o);
        p2 += __shfl_xor(p2, o);
    }
    if (j == 0) {
        atomicAdd(&h2[(size_t)n * 3 + 0], p0);
        atomicAdd(&h2[(size_t)n * 3 + 1], p1);
        atomicAdd(&h2[(size_t)n * 3 + 2], p2);
    }
}

// ==================== layer-2 aggregation + final projection ====================
__global__ __launch_bounds__(384) void k_agg2f(
        const float* __restrict__ h2,
        const int* __restrict__ deg, const int* __restrict__ start,
        const unsigned short* __restrict__ csr,
        const float* __restrict__ as1, const float* __restrict__ ad1,
        const float* __restrict__ as2, const float* __restrict__ ad2,
        const float* __restrict__ as3, const float* __restrict__ ad3,
        const float* __restrict__ b1, const float* __restrict__ b2,
        const float* __restrict__ b3,
        const float* __restrict__ ln_w, const float* __restrict__ ln_b,
        float* __restrict__ out, int E, int N) {
    __shared__ float ys[48];
    int tl = threadIdx.x;
    int pl = tl >> 3;                 // unit 0..47
    int q  = tl & 7;                  // lane in unit
    int id = blockIdx.x * 48 + pl;
    bool valid = id < 3 * N;
    int n = id / 3;
    int r = id - 3 * n;
    float denom = 0.f, acc = 0.f;
    if (valid) {
        float a_s = ((r == 0) ? as1 : (r == 1) ? as2 : as3)[0];
        float a_d = ((r == 0) ? ad1 : (r == 1) ? ad2 : ad3)[0];
        int s0 = start[(size_t)r * N + n];
        int d  = deg[(size_t)r * N + n];
        float hd = h2[id];
        float sd = a_d * hd;
        const unsigned short* cs = csr + (size_t)r * E + s0;
        for (int i = q; i < d; i += 8) {
            float hs = h2[(size_t)cs[i] * 3 + r];
            float e2 = __expf(lrelu(fmaf(a_s, hs, sd)));
            denom += e2;
            acc = fmaf(e2, hs, acc);
        }
        if (q == 0) {
            float ev = __expf(lrelu(fmaf(a_s, hd, sd)));
            denom += ev;
            acc = fmaf(ev, hd, acc);
        }
    }
    denom += __shfl_xor(denom, 1); denom += __shfl_xor(denom, 2); denom += __shfl_xor(denom, 4);
    acc   += __shfl_xor(acc, 1);   acc   += __shfl_xor(acc, 2);   acc   += __shfl_xor(acc, 4);
    if (valid && q == 0) {
        float b = ((r == 0) ? b1 : (r == 1) ? b2 : b3)[0];
        ys[pl] = (acc / (denom + 1e-16f) + b) * ln_w[r];
    }
    __syncthreads();
    if (valid && q == 0 && r == 0)
        out[n] = ys[pl] + ys[pl + 1] + ys[pl + 2] + ln_b[0];
}

extern "C" void kernel_launch(void* const* d_in, const int* in_sizes, int n_in,
                              void* d_out, int out_size, void* d_ws, size_t ws_size,
                              hipStream_t stream) {
    const float* X  = (const float*)d_in[0];
    const int*   A1 = (const int*)d_in[1];
    const int*   A2 = (const int*)d_in[2];
    const int*   A3 = (const int*)d_in[3];
    const float* W11 = (const float*)d_in[5];
    const float* as11 = (const float*)d_in[6];
    const float* ad11 = (const float*)d_in[7];
    const float* b11 = (const float*)d_in[8];
    const float* W12 = (const float*)d_in[9];
    const float* as12 = (const float*)d_in[10];
    const float* ad12 = (const float*)d_in[11];
    const float* b12 = (const float*)d_in[12];
    const float* W21 = (const float*)d_in[13];
    const float* as21 = (const float*)d_in[14];
    const float* ad21 = (const float*)d_in[15];
    const float* b21 = (const float*)d_in[16];
    const float* W22 = (const float*)d_in[17];
    const float* as22 = (const float*)d_in[18];
    const float* ad22 = (const float*)d_in[19];
    const float* b22 = (const float*)d_in[20];
    const float* W31 = (const float*)d_in[21];
    const float* as31 = (const float*)d_in[22];
    const float* ad31 = (const float*)d_in[23];
    const float* b31 = (const float*)d_in[24];
    const float* W32 = (const float*)d_in[25];
    const float* as32 = (const float*)d_in[26];
    const float* ad32 = (const float*)d_in[27];
    const float* b32 = (const float*)d_in[28];
    const float* ln_w = (const float*)d_in[29];
    const float* ln_b = (const float*)d_in[30];

    const int N = in_sizes[0] / 64;
    const int E = in_sizes[1] / 2;
    const int total = 3 * N;
    const int nbA = (total + 1023) / 1024;
    const int nL1 = (N + L1_NODES - 1) / L1_NODES;
    const int nbE = (E + 383) / 384;

    // workspace layout
    float* w = (float*)d_ws;
    float* s_src1 = w; w += (size_t)N * 24;
    float* s_dst1 = w; w += (size_t)N * 24;
    float* h2     = w; w += (size_t)N * 3;
    unsigned short* h_bf = (unsigned short*)w; w += (size_t)N * 192;  // N*384 bf16
    int* iw     = (int*)w;
    int* deg    = iw; iw += (size_t)3 * N;
    int* start  = iw; iw += (size_t)3 * N;
    int* bsum   = iw; iw += 1024;
    int* deg8   = iw; iw += (size_t)24 * N;
    int* startk = iw; iw += (size_t)24 * N;
    unsigned short* epos = (unsigned short*)iw;
    unsigned short* csr  = epos + (size_t)3 * E;

    const int BLK = 256;

    hipMemsetAsync(deg8, 0, (size_t)24 * N * sizeof(int), stream);

    // ---- fused: linear1 ∥ degpos (linear1 blocks first: compute fills CUs,
    //      trailing atomic blocks hide in the gaps — R14 showed reversing this
    //      costs +43 µs) ----
    k_lin1_deg<<<nL1 + 3 * nbE, 384, 0, stream>>>(
        X, W11, W21, W31, as11, ad11, as21, ad21, as31, ad31,
        h_bf, s_src1, s_dst1,
        A1, A2, A3, deg8, epos, nL1, nbE, E, N);

    // ---- CSR scans + scatter ----
    k_scanA2<<<nbA, 256, 0, stream>>>(deg8, deg, startk, start, bsum, total, N);
    k_scanB<<<1, 256, 0, stream>>>(bsum, nbA);
    k_scanC2<<<(total + BLK - 1) / BLK, BLK, 0, stream>>>(start, bsum, startk, h2, total, N, E);
    {
        dim3 grid((E + BLK - 1) / BLK, 3);
        k_scatter2<<<grid, BLK, 0, stream>>>(A1, A2, A3, startk, epos, csr, E, N);
    }

    // ---- layer-1 aggregation (+ fused layer-2 linear) ----
    {
        dim3 grid(N, 3);
        k_agg1<<<grid, 64, 0, stream>>>(h_bf, s_src1, s_dst1, deg, start, csr,
                                        b11, b21, b31, W12, W22, W32, h2, E, N);
    }

    // ---- layer-2 aggregation + final projection ----
    {
        int nb = (total + 47) / 48;
        k_agg2f<<<nb, 384, 0, stream>>>(
            h2, deg, start, csr,
            as12, ad12, as22, ad22, as32, ad32,
            b12, b22, b32, ln_w, ln_b, (float*)d_out, E, N);
    }
}

// Round 16
// 329.607 us; speedup vs baseline: 1.4097x; 1.1448x over previous
//
#include <hip/hip_runtime.h>
#include <cstdint>
#include <cstddef>

#define NEG_SLOPE 0.2f
#define L1_NODES 64
#define EPT 5
#define EPB (384 * EPT)   // edges per bucket-pass block

__device__ __forceinline__ float lrelu(float v) { return v >= 0.f ? v : NEG_SLOPE * v; }

__device__ __forceinline__ unsigned short f2bf(float x) {
    union { float f; uint32_t u; } v; v.f = x;
    uint32_t r = v.u + 0x7FFFu + ((v.u >> 16) & 1u);
    return (unsigned short)(r >> 16);
}
__device__ __forceinline__ float bf2f_lo(uint32_t u) {
    union { uint32_t u; float f; } v; v.u = u << 16;
    return v.f;
}
__device__ __forceinline__ float bf2f_hi(uint32_t u) {
    union { uint32_t u; float f; } v; v.u = u & 0xFFFF0000u;
    return v.f;
}

// ==================== P1: per-block LDS bucket histogram ====================
// bucket = dst >> 7 (128 nodes/bucket). bofs[(r*nbP+blk)*NB + b] = count.
__global__ __launch_bounds__(384) void k_p1(
        const int* __restrict__ A1, const int* __restrict__ A2,
        const int* __restrict__ A3,
        int* __restrict__ bofs, int nbP, int NB, int E) {
    __shared__ int hist[512];
    int t = threadIdx.x, blk = blockIdx.x, r = blockIdx.y;
    for (int i = t; i < NB; i += 384) hist[i] = 0;
    __syncthreads();
    const int* A = (r == 0) ? A1 : (r == 1) ? A2 : A3;
    int base = blk * EPB;
    #pragma unroll
    for (int it = 0; it < EPT; ++it) {
        int e = base + it * 384 + t;
        if (e < E) atomicAdd(&hist[A[E + e] >> 7], 1);
    }
    __syncthreads();
    for (int i = t; i < NB; i += 384)
        bofs[(size_t)(r * nbP + blk) * NB + i] = hist[i];
}

// ==================== P2a: exclusive scan over blocks, per (r, bucket) ====================
__global__ __launch_bounds__(512) void k_p2a(
        int* __restrict__ bofs, int* __restrict__ gbkt, int nbP, int NB) {
    __shared__ int arr[512];
    int t = threadIdx.x, b = blockIdx.x, r = blockIdx.y;
    int v = (t < nbP) ? bofs[(size_t)(r * nbP + t) * NB + b] : 0;
    arr[t] = v; __syncthreads();
    for (int off = 1; off < 512; off <<= 1) {
        int x = (t >= off) ? arr[t - off] : 0; __syncthreads();
        arr[t] += x; __syncthreads();
    }
    if (t < nbP) bofs[(size_t)(r * nbP + t) * NB + b] = arr[t] - v;
    if (t == 0) gbkt[r * NB + b] = arr[nbP - 1];   // bucket total
}

// ==================== P2b: exclusive scan of bucket totals per branch ====================
__global__ __launch_bounds__(512) void k_p2b(
        const int* __restrict__ gbkt, int* __restrict__ gstart, int NB) {
    __shared__ int arr[512];
    int t = threadIdx.x;
    for (int r = 0; r < 3; ++r) {
        int v = (t < NB) ? gbkt[r * NB + t] : 0;
        arr[t] = v; __syncthreads();
        for (int off = 1; off < 512; off <<= 1) {
            int x = (t >= off) ? arr[t - off] : 0; __syncthreads();
            arr[t] += x; __syncthreads();
        }
        if (t < NB) gstart[r * NB + t] = arr[t] - v;
        __syncthreads();
    }
}

// ==================== P3 (fused with linear1): bucket scatter ====================
// blocks [0, nL1): layer-1 linear + scores (compute fills CUs)
// blocks [nL1, nL1+3*nbP): scatter edges into bucket-sorted ebuf (LDS cursors only)
__global__ __launch_bounds__(384) void k_p3_lin1(
        const float* __restrict__ X,
        const float* __restrict__ W1, const float* __restrict__ W2,
        const float* __restrict__ W3,
        const float* __restrict__ as1, const float* __restrict__ ad1,
        const float* __restrict__ as2, const float* __restrict__ ad2,
        const float* __restrict__ as3, const float* __restrict__ ad3,
        unsigned short* __restrict__ h_bf,
        float* __restrict__ s_src, float* __restrict__ s_dst,
        const int* __restrict__ A1, const int* __restrict__ A2,
        const int* __restrict__ A3,
        const int* __restrict__ bofs, const int* __restrict__ gstart,
        uint32_t* __restrict__ ebuf,
        int nL1, int nbP, int NB, int E, int N) {
    int t = threadIdx.x;
    if (blockIdx.x >= (unsigned)nL1) {
        // ---- bucket scatter path ----
        __shared__ int cur[512];
        int b2 = blockIdx.x - nL1;
        int r = b2 / nbP, blk = b2 - r * nbP;
        for (int i = t; i < NB; i += 384) cur[i] = 0;
        __syncthreads();
        const int* A = (r == 0) ? A1 : (r == 1) ? A2 : A3;
        int base = blk * EPB;
        const int* bo = bofs + (size_t)(r * nbP + blk) * NB;
        const int* gs = gstart + r * NB;
        uint32_t* eb = ebuf + (size_t)r * E;
        #pragma unroll
        for (int it = 0; it < EPT; ++it) {
            int e = base + it * 384 + t;
            if (e < E) {
                int dst = A[E + e], src = A[e];
                int b = dst >> 7;
                int rank = atomicAdd(&cur[b], 1);
                int pos = gs[b] + bo[b] + rank;
                eb[pos] = ((uint32_t)src << 7) | (uint32_t)(dst & 127);
            }
        }
        return;
    }
    // ---- linear1 path ----
    __shared__ float Xs[L1_NODES][64];
    int n0 = blockIdx.x * L1_NODES;
    {
        const float4* X4 = reinterpret_cast<const float4*>(X);
        float4* Xs4 = reinterpret_cast<float4*>(&Xs[0][0]);
        for (int i = t; i < L1_NODES * 16; i += 384) {
            int nl = i >> 4;
            float4 xv = make_float4(0.f, 0.f, 0.f, 0.f);
            if (n0 + nl < N) xv = X4[(size_t)(n0 + nl) * 16 + (i & 15)];
            Xs4[i] = xv;
        }
    }
    int r = t >> 7, col = t & 127, head = (t >> 4) & 7, c = t & 15;
    const float* Wp = ((r == 0) ? W1 : (r == 1) ? W2 : W3) + col;
    float Wc[64];
    #pragma unroll
    for (int k = 0; k < 64; ++k) Wc[k] = Wp[(size_t)k * 128];
    float as_v = ((r == 0) ? as1 : (r == 1) ? as2 : as3)[head * 16 + c];
    float ad_v = ((r == 0) ? ad1 : (r == 1) ? ad2 : ad3)[head * 16 + c];
    __syncthreads();
    int nmax = min(L1_NODES, N - n0);
    int rh = (r << 3) + head;
    for (int n = 0; n < nmax; ++n) {
        const float4* xr = reinterpret_cast<const float4*>(&Xs[n][0]);
        float a0 = 0.f, a1 = 0.f, a2 = 0.f, a3 = 0.f;
        #pragma unroll
        for (int k4 = 0; k4 < 16; ++k4) {
            float4 xv = xr[k4];
            a0 = fmaf(xv.x, Wc[k4 * 4 + 0], a0);
            a1 = fmaf(xv.y, Wc[k4 * 4 + 1], a1);
            a2 = fmaf(xv.z, Wc[k4 * 4 + 2], a2);
            a3 = fmaf(xv.w, Wc[k4 * 4 + 3], a3);
        }
        float acc = (a0 + a1) + (a2 + a3);
        h_bf[(size_t)(n0 + n) * 384 + t] = f2bf(acc);
        float ss = acc * as_v, sd = acc * ad_v;
        ss += __shfl_xor(ss, 1); ss += __shfl_xor(ss, 2);
        ss += __shfl_xor(ss, 4); ss += __shfl_xor(ss, 8);
        sd += __shfl_xor(sd, 1); sd += __shfl_xor(sd, 2);
        sd += __shfl_xor(sd, 4); sd += __shfl_xor(sd, 8);
        if (c == 0) {
            s_src[(size_t)(n0 + n) * 24 + rh] = ss;
            s_dst[(size_t)(n0 + n) * 24 + rh] = sd;
        }
    }
}

// ==================== P4: per-bucket CSR finalize (LDS count/scan/scatter) ====================
__global__ __launch_bounds__(256) void k_p4(
        const uint32_t* __restrict__ ebuf,
        const int* __restrict__ gstart, const int* __restrict__ gbkt,
        unsigned short* __restrict__ csr,
        int* __restrict__ deg, int* __restrict__ start,
        int NB, int E, int N) {
    __shared__ int dcnt[128], dst_[128], dcur[128], tmp[128];
    int t = threadIdx.x, b = blockIdx.x, r = blockIdx.y;
    if (t < 128) { dcnt[t] = 0; dcur[t] = 0; }
    __syncthreads();
    int base = gstart[r * NB + b];
    int m    = gbkt[r * NB + b];
    const uint32_t* eb = ebuf + (size_t)r * E + base;
    for (int i = t; i < m; i += 256) atomicAdd(&dcnt[eb[i] & 127], 1);
    __syncthreads();
    if (t < 128) tmp[t] = dcnt[t];
    __syncthreads();
    #pragma unroll
    for (int off = 1; off < 128; off <<= 1) {
        int x = (t < 128 && t >= off) ? tmp[t - off] : 0; __syncthreads();
        if (t < 128) tmp[t] += x; __syncthreads();
    }
    if (t < 128) {
        dst_[t] = tmp[t] - dcnt[t];
        int node = b * 128 + t;
        if (node < N) {
            deg[(size_t)r * N + node]   = dcnt[t];
            start[(size_t)r * N + node] = base + dst_[t];
        }
    }
    __syncthreads();
    unsigned short* cs = csr + (size_t)r * E + base;
    for (int i = t; i < m; i += 256) {
        uint32_t u = eb[i];
        int dl = u & 127;
        int rank = atomicAdd(&dcur[dl], 1);
        cs[dst_[dl] + rank] = (unsigned short)(u >> 7);
    }
}

// ==================== layer-1 aggregation + fused layer-2 linear ====================
__global__ __launch_bounds__(64) void k_agg1(
        const unsigned short* __restrict__ h_bf,
        const float* __restrict__ s_src, const float* __restrict__ s_dst,
        const int* __restrict__ deg, const int* __restrict__ start,
        const unsigned short* __restrict__ csr,
        const float* __restrict__ b1, const float* __restrict__ b2,
        const float* __restrict__ b3,
        const float* __restrict__ W12, const float* __restrict__ W22,
        const float* __restrict__ W32,
        float* __restrict__ h2, int E, int N) {
    __shared__ int sidx[64];
    __shared__ float sex[64 * 8];
    int n = blockIdx.x;
    int r = blockIdx.y;
    int j = threadIdx.x;
    int h = j >> 3;
    int rh = r * 8 + h;
    int s0 = start[(size_t)r * N + n];
    int d  = deg[(size_t)r * N + n];
    const uint32_t* hb = reinterpret_cast<const uint32_t*>(h_bf);
    int off = r * 64 + j;
    float sd = s_dst[(size_t)n * 24 + rh];
    float ex0 = __expf(lrelu(s_src[(size_t)n * 24 + rh] + sd));
    float denom = ex0;
    uint32_t hv0 = hb[(size_t)n * 192 + off];
    float accx = ex0 * bf2f_lo(hv0);
    float accy = ex0 * bf2f_hi(hv0);
    int hA = j & 7;
    float sdA = s_dst[(size_t)n * 24 + r * 8 + hA];
    const unsigned short* cs = csr + (size_t)r * E + s0;
    for (int c0 = 0; c0 < d; c0 += 64) {
        int dc = min(64, d - c0);
        if (j < dc) sidx[j] = cs[c0 + j];
        __syncthreads();
        for (int p = j; p < dc * 8; p += 64) {
            int i = p >> 3;
            float ssv = s_src[(size_t)sidx[i] * 24 + r * 8 + hA];
            sex[p] = __expf(lrelu(ssv + sdA));
        }
        __syncthreads();
        for (int i = 0; i < dc; ++i) {
            float ex = sex[i * 8 + h];
            uint32_t hv = hb[(size_t)sidx[i] * 192 + off];
            denom += ex;
            accx = fmaf(ex, bf2f_lo(hv), accx);
            accy = fmaf(ex, bf2f_hi(hv), accy);
        }
        __syncthreads();
    }
    const float* b = (r == 0) ? b1 : (r == 1) ? b2 : b3;
    float inv = 1.0f / (denom + 1e-16f);
    float ox = accx * inv + b[2 * j];
    float oy = accy * inv + b[2 * j + 1];
    ox = (ox > 0.f) ? ox : 0.f;
    oy = (oy > 0.f) ? oy : 0.f;
    int cbase = r * 128 + 2 * j;
    float p0 = ox * W12[cbase] + oy * W12[cbase + 1];
    float p1 = ox * W22[cbase] + oy * W22[cbase + 1];
    float p2 = ox * W32[cbase] + oy * W32[cbase + 1];
    #pragma unroll
    for (int o = 32; o > 0; o >>= 1) {
        p0 += __shfl_xor(p0, o);
        p1 += __shfl_xor(p1, o);
        p2 += __shfl_xor(p2, o);
    }
    if (j == 0) {
        atomicAdd(&h2[(size_t)n * 3 + 0], p0);
        atomicAdd(&h2[(size_t)n * 3 + 1], p1);
        atomicAdd(&h2[(size_t)n * 3 + 2], p2);
    }
}

// ==================== layer-2 aggregation + final projection ====================
__global__ __launch_bounds__(384) void k_agg2f(
        const float* __restrict__ h2,
        const int* __restrict__ deg, const int* __restrict__ start,
        const unsigned short* __restrict__ csr,
        const float* __restrict__ as1, const float* __restrict__ ad1,
        const float* __restrict__ as2, const float* __restrict__ ad2,
        const float* __restrict__ as3, const float* __restrict__ ad3,
        const float* __restrict__ b1, const float* __restrict__ b2,
        const float* __restrict__ b3,
        const float* __restrict__ ln_w, const float* __restrict__ ln_b,
        float* __restrict__ out, int E, int N) {
    __shared__ float ys[48];
    int tl = threadIdx.x;
    int pl = tl >> 3;
    int q  = tl & 7;
    int id = blockIdx.x * 48 + pl;
    bool valid = id < 3 * N;
    int n = id / 3;
    int r = id - 3 * n;
    float denom = 0.f, acc = 0.f;
    if (valid) {
        float a_s = ((r == 0) ? as1 : (r == 1) ? as2 : as3)[0];
        float a_d = ((r == 0) ? ad1 : (r == 1) ? ad2 : ad3)[0];
        int s0 = start[(size_t)r * N + n];
        int d  = deg[(size_t)r * N + n];
        float hd = h2[id];
        float sd = a_d * hd;
        const unsigned short* cs = csr + (size_t)r * E + s0;
        for (int i = q; i < d; i += 8) {
            float hs = h2[(size_t)cs[i] * 3 + r];
            float e2 = __expf(lrelu(fmaf(a_s, hs, sd)));
            denom += e2;
            acc = fmaf(e2, hs, acc);
        }
        if (q == 0) {
            float ev = __expf(lrelu(fmaf(a_s, hd, sd)));
            denom += ev;
            acc = fmaf(ev, hd, acc);
        }
    }
    denom += __shfl_xor(denom, 1); denom += __shfl_xor(denom, 2); denom += __shfl_xor(denom, 4);
    acc   += __shfl_xor(acc, 1);   acc   += __shfl_xor(acc, 2);   acc   += __shfl_xor(acc, 4);
    if (valid && q == 0) {
        float b = ((r == 0) ? b1 : (r == 1) ? b2 : b3)[0];
        ys[pl] = (acc / (denom + 1e-16f) + b) * ln_w[r];
    }
    __syncthreads();
    if (valid && q == 0 && r == 0)
        out[n] = ys[pl] + ys[pl + 1] + ys[pl + 2] + ln_b[0];
}

extern "C" void kernel_launch(void* const* d_in, const int* in_sizes, int n_in,
                              void* d_out, int out_size, void* d_ws, size_t ws_size,
                              hipStream_t stream) {
    const float* X  = (const float*)d_in[0];
    const int*   A1 = (const int*)d_in[1];
    const int*   A2 = (const int*)d_in[2];
    const int*   A3 = (const int*)d_in[3];
    const float* W11 = (const float*)d_in[5];
    const float* as11 = (const float*)d_in[6];
    const float* ad11 = (const float*)d_in[7];
    const float* b11 = (const float*)d_in[8];
    const float* W12 = (const float*)d_in[9];
    const float* as12 = (const float*)d_in[10];
    const float* ad12 = (const float*)d_in[11];
    const float* b12 = (const float*)d_in[12];
    const float* W21 = (const float*)d_in[13];
    const float* as21 = (const float*)d_in[14];
    const float* ad21 = (const float*)d_in[15];
    const float* b21 = (const float*)d_in[16];
    const float* W22 = (const float*)d_in[17];
    const float* as22 = (const float*)d_in[18];
    const float* ad22 = (const float*)d_in[19];
    const float* b22 = (const float*)d_in[20];
    const float* W31 = (const float*)d_in[21];
    const float* as31 = (const float*)d_in[22];
    const float* ad31 = (const float*)d_in[23];
    const float* b31 = (const float*)d_in[24];
    const float* W32 = (const float*)d_in[25];
    const float* as32 = (const float*)d_in[26];
    const float* ad32 = (const float*)d_in[27];
    const float* b32 = (const float*)d_in[28];
    const float* ln_w = (const float*)d_in[29];
    const float* ln_b = (const float*)d_in[30];

    const int N = in_sizes[0] / 64;
    const int E = in_sizes[1] / 2;
    const int NB  = (N + 127) >> 7;          // dst buckets (<=512)
    const int nbP = (E + EPB - 1) / EPB;     // edge-pass blocks per branch (<=512)
    const int nL1 = (N + L1_NODES - 1) / L1_NODES;

    // workspace layout
    float* w = (float*)d_ws;
    float* s_src1 = w; w += (size_t)N * 24;
    float* s_dst1 = w; w += (size_t)N * 24;
    float* h2     = w; w += (size_t)N * 3;
    unsigned short* h_bf = (unsigned short*)w; w += (size_t)N * 192;  // N*384 bf16
    int* iw     = (int*)w;
    int* deg    = iw; iw += (size_t)3 * N;
    int* start  = iw; iw += (size_t)3 * N;
    int* gbkt   = iw; iw += (size_t)3 * NB;
    int* gstart = iw; iw += (size_t)3 * NB;
    int* bofs   = iw; iw += (size_t)3 * nbP * NB;
    uint32_t* ebuf = (uint32_t*)iw; iw += (size_t)3 * E;
    unsigned short* csr = (unsigned short*)iw;

    hipMemsetAsync(h2, 0, (size_t)3 * N * sizeof(float), stream);

    // ---- CSR build: LDS-atomic counting sort (zero global atomics) ----
    k_p1<<<dim3(nbP, 3), 384, 0, stream>>>(A1, A2, A3, bofs, nbP, NB, E);
    k_p2a<<<dim3(NB, 3), 512, 0, stream>>>(bofs, gbkt, nbP, NB);
    k_p2b<<<1, 512, 0, stream>>>(gbkt, gstart, NB);
    // ---- fused: linear1 (compute) ∥ bucket scatter ----
    k_p3_lin1<<<nL1 + 3 * nbP, 384, 0, stream>>>(
        X, W11, W21, W31, as11, ad11, as21, ad21, as31, ad31,
        h_bf, s_src1, s_dst1,
        A1, A2, A3, bofs, gstart, ebuf, nL1, nbP, NB, E, N);
    k_p4<<<dim3(NB, 3), 256, 0, stream>>>(ebuf, gstart, gbkt, csr, deg, start, NB, E, N);

    // ---- layer-1 aggregation (+ fused layer-2 linear) ----
    {
        dim3 grid(N, 3);
        k_agg1<<<grid, 64, 0, stream>>>(h_bf, s_src1, s_dst1, deg, start, csr,
                                        b11, b21, b31, W12, W22, W32, h2, E, N);
    }

    // ---- layer-2 aggregation + final projection ----
    {
        int nb = (3 * N + 47) / 48;
        k_agg2f<<<nb, 384, 0, stream>>>(
            h2, deg, start, csr,
            as12, ad12, as22, ad22, as32, ad32,
            b12, b22, b32, ln_w, ln_b, (float*)d_out, E, N);
    }
}

// Round 17
// 322.566 us; speedup vs baseline: 1.4404x; 1.0218x over previous
//
#include <hip/hip_runtime.h>
#include <cstdint>
#include <cstddef>

#define NEG_SLOPE 0.2f
#define L1_NODES 64
#define EPT 32
#define EPB (384 * EPT)   // edges per bucket-pass block (12288)

__device__ __forceinline__ float lrelu(float v) { return v >= 0.f ? v : NEG_SLOPE * v; }

__device__ __forceinline__ unsigned short f2bf(float x) {
    union { float f; uint32_t u; } v; v.f = x;
    uint32_t r = v.u + 0x7FFFu + ((v.u >> 16) & 1u);
    return (unsigned short)(r >> 16);
}
__device__ __forceinline__ float bf2f_lo(uint32_t u) {
    union { uint32_t u; float f; } v; v.u = u << 16;
    return v.f;
}
__device__ __forceinline__ float bf2f_hi(uint32_t u) {
    union { uint32_t u; float f; } v; v.u = u & 0xFFFF0000u;
    return v.f;
}

// ==================== P1: per-block LDS bucket histogram (+ h2 zero) ====================
// bucket = dst >> 7 (128 nodes/bucket). bofs[(r*nbP+blk)*NB + b] = count.
__global__ __launch_bounds__(384) void k_p1(
        const int* __restrict__ A1, const int* __restrict__ A2,
        const int* __restrict__ A3,
        int* __restrict__ bofs, float* __restrict__ h2,
        int nbP, int NB, int E, int N) {
    __shared__ int hist[512];
    int t = threadIdx.x, blk = blockIdx.x, r = blockIdx.y;
    for (int i = t; i < NB; i += 384) hist[i] = 0;
    // fold h2 zeroing into this pass (grid-linear stride)
    {
        int id = (r * nbP + blk) * 384 + t;
        int stride = 3 * nbP * 384;
        for (int i = id; i < 3 * N; i += stride) h2[i] = 0.f;
    }
    __syncthreads();
    const int* A = (r == 0) ? A1 : (r == 1) ? A2 : A3;
    int base = blk * EPB;
    #pragma unroll
    for (int it = 0; it < EPT; ++it) {
        int e = base + it * 384 + t;
        if (e < E) atomicAdd(&hist[A[E + e] >> 7], 1);
    }
    __syncthreads();
    for (int i = t; i < NB; i += 384)
        bofs[(size_t)(r * nbP + blk) * NB + i] = hist[i];
}

// ==================== P2a: exclusive scan over blocks, per (r, bucket) ====================
__global__ __launch_bounds__(512) void k_p2a(
        int* __restrict__ bofs, int* __restrict__ gbkt, int nbP, int NB) {
    __shared__ int arr[512];
    int t = threadIdx.x, b = blockIdx.x, r = blockIdx.y;
    int v = (t < nbP) ? bofs[(size_t)(r * nbP + t) * NB + b] : 0;
    arr[t] = v; __syncthreads();
    for (int off = 1; off < 512; off <<= 1) {
        int x = (t >= off) ? arr[t - off] : 0; __syncthreads();
        arr[t] += x; __syncthreads();
    }
    if (t < nbP) bofs[(size_t)(r * nbP + t) * NB + b] = arr[t] - v;
    if (t == 0) gbkt[r * NB + b] = arr[511];   // bucket total (inclusive over all blocks)
}

// ==================== P2b: exclusive scan of bucket totals per branch ====================
__global__ __launch_bounds__(512) void k_p2b(
        const int* __restrict__ gbkt, int* __restrict__ gstart, int NB) {
    __shared__ int arr[512];
    int t = threadIdx.x;
    for (int r = 0; r < 3; ++r) {
        int v = (t < NB) ? gbkt[r * NB + t] : 0;
        arr[t] = v; __syncthreads();
        for (int off = 1; off < 512; off <<= 1) {
            int x = (t >= off) ? arr[t - off] : 0; __syncthreads();
            arr[t] += x; __syncthreads();
        }
        if (t < NB) gstart[r * NB + t] = arr[t] - v;
        __syncthreads();
    }
}

// ==================== P3 (fused with linear1): bucket scatter ====================
// blocks [0, nL1): layer-1 linear + scores (compute fills CUs)
// blocks [nL1, nL1+3*nbP): scatter edges into bucket-sorted ebuf (LDS cursors only)
__global__ __launch_bounds__(384) void k_p3_lin1(
        const float* __restrict__ X,
        const float* __restrict__ W1, const float* __restrict__ W2,
        const float* __restrict__ W3,
        const float* __restrict__ as1, const float* __restrict__ ad1,
        const float* __restrict__ as2, const float* __restrict__ ad2,
        const float* __restrict__ as3, const float* __restrict__ ad3,
        unsigned short* __restrict__ h_bf,
        float* __restrict__ s_src, float* __restrict__ s_dst,
        const int* __restrict__ A1, const int* __restrict__ A2,
        const int* __restrict__ A3,
        const int* __restrict__ bofs, const int* __restrict__ gstart,
        uint32_t* __restrict__ ebuf,
        int nL1, int nbP, int NB, int E, int N) {
    int t = threadIdx.x;
    if (blockIdx.x >= (unsigned)nL1) {
        // ---- bucket scatter path ----
        __shared__ int cur[512];
        int b2 = blockIdx.x - nL1;
        int r = b2 / nbP, blk = b2 - r * nbP;
        for (int i = t; i < NB; i += 384) cur[i] = 0;
        __syncthreads();
        const int* A = (r == 0) ? A1 : (r == 1) ? A2 : A3;
        int base = blk * EPB;
        const int* bo = bofs + (size_t)(r * nbP + blk) * NB;
        const int* gs = gstart + r * NB;
        uint32_t* eb = ebuf + (size_t)r * E;
        #pragma unroll 4
        for (int it = 0; it < EPT; ++it) {
            int e = base + it * 384 + t;
            if (e < E) {
                int dst = A[E + e], src = A[e];
                int b = dst >> 7;
                int rank = atomicAdd(&cur[b], 1);
                int pos = gs[b] + bo[b] + rank;
                eb[pos] = ((uint32_t)src << 7) | (uint32_t)(dst & 127);
            }
        }
        return;
    }
    // ---- linear1 path ----
    __shared__ float Xs[L1_NODES][64];
    int n0 = blockIdx.x * L1_NODES;
    {
        const float4* X4 = reinterpret_cast<const float4*>(X);
        float4* Xs4 = reinterpret_cast<float4*>(&Xs[0][0]);
        for (int i = t; i < L1_NODES * 16; i += 384) {
            int nl = i >> 4;
            float4 xv = make_float4(0.f, 0.f, 0.f, 0.f);
            if (n0 + nl < N) xv = X4[(size_t)(n0 + nl) * 16 + (i & 15)];
            Xs4[i] = xv;
        }
    }
    int r = t >> 7, col = t & 127, head = (t >> 4) & 7, c = t & 15;
    const float* Wp = ((r == 0) ? W1 : (r == 1) ? W2 : W3) + col;
    float Wc[64];
    #pragma unroll
    for (int k = 0; k < 64; ++k) Wc[k] = Wp[(size_t)k * 128];
    float as_v = ((r == 0) ? as1 : (r == 1) ? as2 : as3)[head * 16 + c];
    float ad_v = ((r == 0) ? ad1 : (r == 1) ? ad2 : ad3)[head * 16 + c];
    __syncthreads();
    int nmax = min(L1_NODES, N - n0);
    int rh = (r << 3) + head;
    for (int n = 0; n < nmax; ++n) {
        const float4* xr = reinterpret_cast<const float4*>(&Xs[n][0]);
        float a0 = 0.f, a1 = 0.f, a2 = 0.f, a3 = 0.f;
        #pragma unroll
        for (int k4 = 0; k4 < 16; ++k4) {
            float4 xv = xr[k4];
            a0 = fmaf(xv.x, Wc[k4 * 4 + 0], a0);
            a1 = fmaf(xv.y, Wc[k4 * 4 + 1], a1);
            a2 = fmaf(xv.z, Wc[k4 * 4 + 2], a2);
            a3 = fmaf(xv.w, Wc[k4 * 4 + 3], a3);
        }
        float acc = (a0 + a1) + (a2 + a3);
        h_bf[(size_t)(n0 + n) * 384 + t] = f2bf(acc);
        float ss = acc * as_v, sd = acc * ad_v;
        ss += __shfl_xor(ss, 1); ss += __shfl_xor(ss, 2);
        ss += __shfl_xor(ss, 4); ss += __shfl_xor(ss, 8);
        sd += __shfl_xor(sd, 1); sd += __shfl_xor(sd, 2);
        sd += __shfl_xor(sd, 4); sd += __shfl_xor(sd, 8);
        if (c == 0) {
            s_src[(size_t)(n0 + n) * 24 + rh] = ss;
            s_dst[(size_t)(n0 + n) * 24 + rh] = sd;
        }
    }
}

// ==================== P4: per-bucket CSR finalize (LDS count/scan/scatter) ====================
__global__ __launch_bounds__(512) void k_p4(
        const uint32_t* __restrict__ ebuf,
        const int* __restrict__ gstart, const int* __restrict__ gbkt,
        unsigned short* __restrict__ csr,
        int* __restrict__ deg, int* __restrict__ start,
        int NB, int E, int N) {
    __shared__ int dcnt[128], dst_[128], dcur[128], tmp[128];
    int t = threadIdx.x, b = blockIdx.x, r = blockIdx.y;
    if (t < 128) { dcnt[t] = 0; dcur[t] = 0; }
    __syncthreads();
    int base = gstart[r * NB + b];
    int m    = gbkt[r * NB + b];
    const uint32_t* eb = ebuf + (size_t)r * E + base;
    for (int i = t; i < m; i += 512) atomicAdd(&dcnt[eb[i] & 127], 1);
    __syncthreads();
    if (t < 128) tmp[t] = dcnt[t];
    __syncthreads();
    #pragma unroll
    for (int off = 1; off < 128; off <<= 1) {
        int x = (t < 128 && t >= off) ? tmp[t - off] : 0; __syncthreads();
        if (t < 128) tmp[t] += x; __syncthreads();
    }
    if (t < 128) {
        dst_[t] = tmp[t] - dcnt[t];
        int node = b * 128 + t;
        if (node < N) {
            deg[(size_t)r * N + node]   = dcnt[t];
            start[(size_t)r * N + node] = base + dst_[t];
        }
    }
    __syncthreads();
    unsigned short* cs = csr + (size_t)r * E + base;
    for (int i = t; i < m; i += 512) {
        uint32_t u = eb[i];
        int dl = u & 127;
        int rank = atomicAdd(&dcur[dl], 1);
        cs[dst_[dl] + rank] = (unsigned short)(u >> 7);
    }
}

// ==================== layer-1 aggregation + fused layer-2 linear ====================
__global__ __launch_bounds__(64) void k_agg1(
        const unsigned short* __restrict__ h_bf,
        const float* __restrict__ s_src, const float* __restrict__ s_dst,
        const int* __restrict__ deg, const int* __restrict__ start,
        const unsigned short* __restrict__ csr,
        const float* __restrict__ b1, const float* __restrict__ b2,
        const float* __restrict__ b3,
        const float* __restrict__ W12, const float* __restrict__ W22,
        const float* __restrict__ W32,
        float* __restrict__ h2, int E, int N) {
    __shared__ int sidx[64];
    __shared__ float sex[64 * 8];
    int n = blockIdx.x;
    int r = blockIdx.y;
    int j = threadIdx.x;
    int h = j >> 3;
    int rh = r * 8 + h;
    int s0 = start[(size_t)r * N + n];
    int d  = deg[(size_t)r * N + n];
    const uint32_t* hb = reinterpret_cast<const uint32_t*>(h_bf);
    int off = r * 64 + j;
    float sd = s_dst[(size_t)n * 24 + rh];
    float ex0 = __expf(lrelu(s_src[(size_t)n * 24 + rh] + sd));
    float denom = ex0;
    uint32_t hv0 = hb[(size_t)n * 192 + off];
    float accx = ex0 * bf2f_lo(hv0);
    float accy = ex0 * bf2f_hi(hv0);
    int hA = j & 7;
    float sdA = s_dst[(size_t)n * 24 + r * 8 + hA];
    const unsigned short* cs = csr + (size_t)r * E + s0;
    for (int c0 = 0; c0 < d; c0 += 64) {
        int dc = min(64, d - c0);
        if (j < dc) sidx[j] = cs[c0 + j];
        __syncthreads();
        for (int p = j; p < dc * 8; p += 64) {
            int i = p >> 3;
            float ssv = s_src[(size_t)sidx[i] * 24 + r * 8 + hA];
            sex[p] = __expf(lrelu(ssv + sdA));
        }
        __syncthreads();
        for (int i = 0; i < dc; ++i) {
            float ex = sex[i * 8 + h];
            uint32_t hv = hb[(size_t)sidx[i] * 192 + off];
            denom += ex;
            accx = fmaf(ex, bf2f_lo(hv), accx);
            accy = fmaf(ex, bf2f_hi(hv), accy);
        }
        __syncthreads();
    }
    const float* b = (r == 0) ? b1 : (r == 1) ? b2 : b3;
    float inv = 1.0f / (denom + 1e-16f);
    float ox = accx * inv + b[2 * j];
    float oy = accy * inv + b[2 * j + 1];
    ox = (ox > 0.f) ? ox : 0.f;
    oy = (oy > 0.f) ? oy : 0.f;
    int cbase = r * 128 + 2 * j;
    float p0 = ox * W12[cbase] + oy * W12[cbase + 1];
    float p1 = ox * W22[cbase] + oy * W22[cbase + 1];
    float p2 = ox * W32[cbase] + oy * W32[cbase + 1];
    #pragma unroll
    for (int o = 32; o > 0; o >>= 1) {
        p0 += __shfl_xor(p0, o);
        p1 += __shfl_xor(p1, o);
        p2 += __shfl_xor(p2, o);
    }
    if (j == 0) {
        atomicAdd(&h2[(size_t)n * 3 + 0], p0);
        atomicAdd(&h2[(size_t)n * 3 + 1], p1);
        atomicAdd(&h2[(size_t)n * 3 + 2], p2);
    }
}

// ==================== layer-2 aggregation + final projection ====================
__global__ __launch_bounds__(384) void k_agg2f(
        const float* __restrict__ h2,
        const int* __restrict__ deg, const int* __restrict__ start,
        const unsigned short* __restrict__ csr,
        const float* __restrict__ as1, const float* __restrict__ ad1,
        const float* __restrict__ as2, const float* __restrict__ ad2,
        const float* __restrict__ as3, const float* __restrict__ ad3,
        const float* __restrict__ b1, const float* __restrict__ b2,
        const float* __restrict__ b3,
        const float* __restrict__ ln_w, const float* __restrict__ ln_b,
        float* __restrict__ out, int E, int N) {
    __shared__ float ys[48];
    int tl = threadIdx.x;
    int pl = tl >> 3;
    int q  = tl & 7;
    int id = blockIdx.x * 48 + pl;
    bool valid = id < 3 * N;
    int n = id / 3;
    int r = id - 3 * n;
    float denom = 0.f, acc = 0.f;
    if (valid) {
        float a_s = ((r == 0) ? as1 : (r == 1) ? as2 : as3)[0];
        float a_d = ((r == 0) ? ad1 : (r == 1) ? ad2 : ad3)[0];
        int s0 = start[(size_t)r * N + n];
        int d  = deg[(size_t)r * N + n];
        float hd = h2[id];
        float sd = a_d * hd;
        const unsigned short* cs = csr + (size_t)r * E + s0;
        for (int i = q; i < d; i += 8) {
            float hs = h2[(size_t)cs[i] * 3 + r];
            float e2 = __expf(lrelu(fmaf(a_s, hs, sd)));
            denom += e2;
            acc = fmaf(e2, hs, acc);
        }
        if (q == 0) {
            float ev = __expf(lrelu(fmaf(a_s, hd, sd)));
            denom += ev;
            acc = fmaf(ev, hd, acc);
        }
    }
    denom += __shfl_xor(denom, 1); denom += __shfl_xor(denom, 2); denom += __shfl_xor(denom, 4);
    acc   += __shfl_xor(acc, 1);   acc   += __shfl_xor(acc, 2);   acc   += __shfl_xor(acc, 4);
    if (valid && q == 0) {
        float b = ((r == 0) ? b1 : (r == 1) ? b2 : b3)[0];
        ys[pl] = (acc / (denom + 1e-16f) + b) * ln_w[r];
    }
    __syncthreads();
    if (valid && q == 0 && r == 0)
        out[n] = ys[pl] + ys[pl + 1] + ys[pl + 2] + ln_b[0];
}

extern "C" void kernel_launch(void* const* d_in, const int* in_sizes, int n_in,
                              void* d_out, int out_size, void* d_ws, size_t ws_size,
                              hipStream_t stream) {
    const float* X  = (const float*)d_in[0];
    const int*   A1 = (const int*)d_in[1];
    const int*   A2 = (const int*)d_in[2];
    const int*   A3 = (const int*)d_in[3];
    const float* W11 = (const float*)d_in[5];
    const float* as11 = (const float*)d_in[6];
    const float* ad11 = (const float*)d_in[7];
    const float* b11 = (const float*)d_in[8];
    const float* W12 = (const float*)d_in[9];
    const float* as12 = (const float*)d_in[10];
    const float* ad12 = (const float*)d_in[11];
    const float* b12 = (const float*)d_in[12];
    const float* W21 = (const float*)d_in[13];
    const float* as21 = (const float*)d_in[14];
    const float* ad21 = (const float*)d_in[15];
    const float* b21 = (const float*)d_in[16];
    const float* W22 = (const float*)d_in[17];
    const float* as22 = (const float*)d_in[18];
    const float* ad22 = (const float*)d_in[19];
    const float* b22 = (const float*)d_in[20];
    const float* W31 = (const float*)d_in[21];
    const float* as31 = (const float*)d_in[22];
    const float* ad31 = (const float*)d_in[23];
    const float* b31 = (const float*)d_in[24];
    const float* W32 = (const float*)d_in[25];
    const float* as32 = (const float*)d_in[26];
    const float* ad32 = (const float*)d_in[27];
    const float* b32 = (const float*)d_in[28];
    const float* ln_w = (const float*)d_in[29];
    const float* ln_b = (const float*)d_in[30];

    const int N = in_sizes[0] / 64;
    const int E = in_sizes[1] / 2;
    const int NB  = (N + 127) >> 7;          // dst buckets (<=512)
    const int nbP = (E + EPB - 1) / EPB;     // edge-pass blocks per branch (<=512)
    const int nL1 = (N + L1_NODES - 1) / L1_NODES;

    // workspace layout
    float* w = (float*)d_ws;
    float* s_src1 = w; w += (size_t)N * 24;
    float* s_dst1 = w; w += (size_t)N * 24;
    float* h2     = w; w += (size_t)N * 3;
    unsigned short* h_bf = (unsigned short*)w; w += (size_t)N * 192;  // N*384 bf16
    int* iw     = (int*)w;
    int* deg    = iw; iw += (size_t)3 * N;
    int* start  = iw; iw += (size_t)3 * N;
    int* gbkt   = iw; iw += (size_t)3 * NB;
    int* gstart = iw; iw += (size_t)3 * NB;
    int* bofs   = iw; iw += (size_t)3 * nbP * NB;
    uint32_t* ebuf = (uint32_t*)iw; iw += (size_t)3 * E;
    unsigned short* csr = (unsigned short*)iw;

    // ---- CSR build: LDS-atomic counting sort (zero global atomics) ----
    k_p1<<<dim3(nbP, 3), 384, 0, stream>>>(A1, A2, A3, bofs, h2, nbP, NB, E, N);
    k_p2a<<<dim3(NB, 3), 512, 0, stream>>>(bofs, gbkt, nbP, NB);
    k_p2b<<<1, 512, 0, stream>>>(gbkt, gstart, NB);
    // ---- fused: linear1 (compute) ∥ bucket scatter ----
    k_p3_lin1<<<nL1 + 3 * nbP, 384, 0, stream>>>(
        X, W11, W21, W31, as11, ad11, as21, ad21, as31, ad31,
        h_bf, s_src1, s_dst1,
        A1, A2, A3, bofs, gstart, ebuf, nL1, nbP, NB, E, N);
    k_p4<<<dim3(NB, 3), 512, 0, stream>>>(ebuf, gstart, gbkt, csr, deg, start, NB, E, N);

    // ---- layer-1 aggregation (+ fused layer-2 linear) ----
    {
        dim3 grid(N, 3);
        k_agg1<<<grid, 64, 0, stream>>>(h_bf, s_src1, s_dst1, deg, start, csr,
                                        b11, b21, b31, W12, W22, W32, h2, E, N);
    }

    // ---- layer-2 aggregation + final projection ----
    {
        int nb = (3 * N + 47) / 48;
        k_agg2f<<<nb, 384, 0, stream>>>(
            h2, deg, start, csr,
            as12, ad12, as22, ad22, as32, ad32,
            b12, b22, b32, ln_w, ln_b, (float*)d_out, E, N);
    }
}

// Round 18
// 316.230 us; speedup vs baseline: 1.4693x; 1.0200x over previous
//
#include <hip/hip_runtime.h>
#include <cstdint>
#include <cstddef>

#define NEG_SLOPE 0.2f
#define L1_NODES 64
#define EPT 32
#define EPB (384 * EPT)   // edges per scatter block (12288)
#define CAP 6144          // fixed slab capacity per (branch, bucket); mean occupancy 2048

__device__ __forceinline__ float lrelu(float v) { return v >= 0.f ? v : NEG_SLOPE * v; }

__device__ __forceinline__ unsigned short f2bf(float x) {
    union { float f; uint32_t u; } v; v.f = x;
    uint32_t r = v.u + 0x7FFFu + ((v.u >> 16) & 1u);
    return (unsigned short)(r >> 16);
}
__device__ __forceinline__ float bf2f_lo(uint32_t u) {
    union { uint32_t u; float f; } v; v.u = u << 16;
    return v.f;
}
__device__ __forceinline__ float bf2f_hi(uint32_t u) {
    union { uint32_t u; float f; } v; v.u = u & 0xFFFF0000u;
    return v.f;
}

// ========== fused: layer-1 linear/scores ∥ slab bucket-scatter (1 edge pass) ==========
// blocks [0, nL1): linear1 tiles (compute fills CUs first — R14 lesson)
// blocks [nL1, nL1+3*nbP): LDS-count -> 1-atomic-per-bucket reserve -> slab scatter
__global__ __launch_bounds__(384) void k_sc_lin1(
        const float* __restrict__ X,
        const float* __restrict__ W1, const float* __restrict__ W2,
        const float* __restrict__ W3,
        const float* __restrict__ as1, const float* __restrict__ ad1,
        const float* __restrict__ as2, const float* __restrict__ ad2,
        const float* __restrict__ as3, const float* __restrict__ ad3,
        unsigned short* __restrict__ h_bf,
        float* __restrict__ s_src, float* __restrict__ s_dst,
        const int* __restrict__ A1, const int* __restrict__ A2,
        const int* __restrict__ A3,
        int* __restrict__ bktcnt, uint32_t* __restrict__ ebuf,
        float* __restrict__ h2,
        int nL1, int nbP, int NB, int E, int N) {
    __shared__ char smem[16384];
    int t = threadIdx.x;
    if (blockIdx.x >= (unsigned)nL1) {
        // ---- slab scatter path ----
        int* hist = reinterpret_cast<int*>(smem);        // [512]
        int* cur  = hist + 512;                          // [512]
        int b2 = blockIdx.x - nL1;
        int r = b2 / nbP, blk = b2 - r * nbP;
        // fold h2 zeroing into this pass
        {
            int gid = b2 * 384 + t, gstride = 3 * nbP * 384;
            for (int i = gid; i < 3 * N; i += gstride) h2[i] = 0.f;
        }
        for (int i = t; i < NB; i += 384) hist[i] = 0;
        __syncthreads();
        const int* A = (r == 0) ? A1 : (r == 1) ? A2 : A3;
        int base = blk * EPB;
        #pragma unroll 4
        for (int it = 0; it < EPT; ++it) {
            int e = base + it * 384 + t;
            if (e < E) atomicAdd(&hist[A[E + e] >> 7], 1);
        }
        __syncthreads();
        for (int i = t; i < NB; i += 384) {
            int c = hist[i];
            cur[i] = c ? atomicAdd(&bktcnt[r * NB + i], c) : 0;
        }
        __syncthreads();
        #pragma unroll 4
        for (int it = 0; it < EPT; ++it) {
            int e = base + it * 384 + t;
            if (e < E) {
                int dst = A[E + e], src = A[e];
                int b = dst >> 7;
                int pos = atomicAdd(&cur[b], 1);
                ebuf[(size_t)(r * NB + b) * CAP + pos] =
                    ((uint32_t)src << 7) | (uint32_t)(dst & 127);
            }
        }
        return;
    }
    // ---- linear1 path ----
    float (*Xs)[64] = reinterpret_cast<float(*)[64]>(smem);
    int n0 = blockIdx.x * L1_NODES;
    {
        const float4* X4 = reinterpret_cast<const float4*>(X);
        float4* Xs4 = reinterpret_cast<float4*>(&Xs[0][0]);
        for (int i = t; i < L1_NODES * 16; i += 384) {
            int nl = i >> 4;
            float4 xv = make_float4(0.f, 0.f, 0.f, 0.f);
            if (n0 + nl < N) xv = X4[(size_t)(n0 + nl) * 16 + (i & 15)];
            Xs4[i] = xv;
        }
    }
    int r = t >> 7, col = t & 127, head = (t >> 4) & 7, c = t & 15;
    const float* Wp = ((r == 0) ? W1 : (r == 1) ? W2 : W3) + col;
    float Wc[64];
    #pragma unroll
    for (int k = 0; k < 64; ++k) Wc[k] = Wp[(size_t)k * 128];
    float as_v = ((r == 0) ? as1 : (r == 1) ? as2 : as3)[head * 16 + c];
    float ad_v = ((r == 0) ? ad1 : (r == 1) ? ad2 : ad3)[head * 16 + c];
    __syncthreads();
    int nmax = min(L1_NODES, N - n0);
    int rh = (r << 3) + head;
    for (int n = 0; n < nmax; ++n) {
        const float4* xr = reinterpret_cast<const float4*>(&Xs[n][0]);
        float a0 = 0.f, a1 = 0.f, a2 = 0.f, a3 = 0.f;
        #pragma unroll
        for (int k4 = 0; k4 < 16; ++k4) {
            float4 xv = xr[k4];
            a0 = fmaf(xv.x, Wc[k4 * 4 + 0], a0);
            a1 = fmaf(xv.y, Wc[k4 * 4 + 1], a1);
            a2 = fmaf(xv.z, Wc[k4 * 4 + 2], a2);
            a3 = fmaf(xv.w, Wc[k4 * 4 + 3], a3);
        }
        float acc = (a0 + a1) + (a2 + a3);
        h_bf[(size_t)(n0 + n) * 384 + t] = f2bf(acc);
        float ss = acc * as_v, sd = acc * ad_v;
        ss += __shfl_xor(ss, 1); ss += __shfl_xor(ss, 2);
        ss += __shfl_xor(ss, 4); ss += __shfl_xor(ss, 8);
        sd += __shfl_xor(sd, 1); sd += __shfl_xor(sd, 2);
        sd += __shfl_xor(sd, 4); sd += __shfl_xor(sd, 8);
        if (c == 0) {
            s_src[(size_t)(n0 + n) * 24 + rh] = ss;
            s_dst[(size_t)(n0 + n) * 24 + rh] = sd;
        }
    }
}

// ========== scan: exclusive scan of bucket totals per branch (1 block) ==========
__global__ __launch_bounds__(512) void k_scan(
        const int* __restrict__ bktcnt, int* __restrict__ gstart, int NB) {
    __shared__ int arr[512];
    int t = threadIdx.x;
    for (int r = 0; r < 3; ++r) {
        int v = (t < NB) ? bktcnt[r * NB + t] : 0;
        arr[t] = v; __syncthreads();
        for (int off = 1; off < 512; off <<= 1) {
            int x = (t >= off) ? arr[t - off] : 0; __syncthreads();
            arr[t] += x; __syncthreads();
        }
        if (t < NB) gstart[r * NB + t] = arr[t] - v;
        __syncthreads();
    }
}

// ========== P4: per-bucket CSR finalize (LDS count/scan/scatter) ==========
__global__ __launch_bounds__(512) void k_p4(
        const uint32_t* __restrict__ ebuf,
        const int* __restrict__ gstart, const int* __restrict__ bktcnt,
        unsigned short* __restrict__ csr,
        int* __restrict__ deg, int* __restrict__ start,
        int NB, int E, int N) {
    __shared__ int dcnt[128], dst_[128], dcur[128], tmp[128];
    int t = threadIdx.x, b = blockIdx.x, r = blockIdx.y;
    if (t < 128) { dcnt[t] = 0; dcur[t] = 0; }
    __syncthreads();
    int base = gstart[r * NB + b];
    int m    = bktcnt[r * NB + b];
    const uint32_t* eb = ebuf + (size_t)(r * NB + b) * CAP;
    for (int i = t; i < m; i += 512) atomicAdd(&dcnt[eb[i] & 127], 1);
    __syncthreads();
    if (t < 128) tmp[t] = dcnt[t];
    __syncthreads();
    #pragma unroll
    for (int off = 1; off < 128; off <<= 1) {
        int x = (t < 128 && t >= off) ? tmp[t - off] : 0; __syncthreads();
        if (t < 128) tmp[t] += x; __syncthreads();
    }
    if (t < 128) {
        dst_[t] = tmp[t] - dcnt[t];
        int node = b * 128 + t;
        if (node < N) {
            deg[(size_t)r * N + node]   = dcnt[t];
            start[(size_t)r * N + node] = base + dst_[t];
        }
    }
    __syncthreads();
    unsigned short* cs = csr + (size_t)r * E + base;
    for (int i = t; i < m; i += 512) {
        uint32_t u = eb[i];
        int dl = u & 127;
        int rank = atomicAdd(&dcur[dl], 1);
        cs[dst_[dl] + rank] = (unsigned short)(u >> 7);
    }
}

// ========== layer-1 aggregation + fused layer-2 linear ==========
__global__ __launch_bounds__(64) void k_agg1(
        const unsigned short* __restrict__ h_bf,
        const float* __restrict__ s_src, const float* __restrict__ s_dst,
        const int* __restrict__ deg, const int* __restrict__ start,
        const unsigned short* __restrict__ csr,
        const float* __restrict__ b1, const float* __restrict__ b2,
        const float* __restrict__ b3,
        const float* __restrict__ W12, const float* __restrict__ W22,
        const float* __restrict__ W32,
        float* __restrict__ h2, int E, int N) {
    __shared__ int sidx[64];
    __shared__ float sex[64 * 8];
    int n = blockIdx.x;
    int r = blockIdx.y;
    int j = threadIdx.x;
    int h = j >> 3;
    int rh = r * 8 + h;
    int s0 = start[(size_t)r * N + n];
    int d  = deg[(size_t)r * N + n];
    const uint32_t* hb = reinterpret_cast<const uint32_t*>(h_bf);
    int off = r * 64 + j;
    float sd = s_dst[(size_t)n * 24 + rh];
    float ex0 = __expf(lrelu(s_src[(size_t)n * 24 + rh] + sd));
    float denom = ex0;
    uint32_t hv0 = hb[(size_t)n * 192 + off];
    float accx = ex0 * bf2f_lo(hv0);
    float accy = ex0 * bf2f_hi(hv0);
    int hA = j & 7;
    float sdA = s_dst[(size_t)n * 24 + r * 8 + hA];
    const unsigned short* cs = csr + (size_t)r * E + s0;
    for (int c0 = 0; c0 < d; c0 += 64) {
        int dc = min(64, d - c0);
        if (j < dc) sidx[j] = cs[c0 + j];
        __syncthreads();
        for (int p = j; p < dc * 8; p += 64) {
            int i = p >> 3;
            float ssv = s_src[(size_t)sidx[i] * 24 + r * 8 + hA];
            sex[p] = __expf(lrelu(ssv + sdA));
        }
        __syncthreads();
        for (int i = 0; i < dc; ++i) {
            float ex = sex[i * 8 + h];
            uint32_t hv = hb[(size_t)sidx[i] * 192 + off];
            denom += ex;
            accx = fmaf(ex, bf2f_lo(hv), accx);
            accy = fmaf(ex, bf2f_hi(hv), accy);
        }
        __syncthreads();
    }
    const float* b = (r == 0) ? b1 : (r == 1) ? b2 : b3;
    float inv = 1.0f / (denom + 1e-16f);
    float ox = accx * inv + b[2 * j];
    float oy = accy * inv + b[2 * j + 1];
    ox = (ox > 0.f) ? ox : 0.f;
    oy = (oy > 0.f) ? oy : 0.f;
    int cbase = r * 128 + 2 * j;
    float p0 = ox * W12[cbase] + oy * W12[cbase + 1];
    float p1 = ox * W22[cbase] + oy * W22[cbase + 1];
    float p2 = ox * W32[cbase] + oy * W32[cbase + 1];
    #pragma unroll
    for (int o = 32; o > 0; o >>= 1) {
        p0 += __shfl_xor(p0, o);
        p1 += __shfl_xor(p1, o);
        p2 += __shfl_xor(p2, o);
    }
    if (j == 0) {
        atomicAdd(&h2[(size_t)n * 3 + 0], p0);
        atomicAdd(&h2[(size_t)n * 3 + 1], p1);
        atomicAdd(&h2[(size_t)n * 3 + 2], p2);
    }
}

// ========== layer-2 aggregation + final projection ==========
__global__ __launch_bounds__(384) void k_agg2f(
        const float* __restrict__ h2,
        const int* __restrict__ deg, const int* __restrict__ start,
        const unsigned short* __restrict__ csr,
        const float* __restrict__ as1, const float* __restrict__ ad1,
        const float* __restrict__ as2, const float* __restrict__ ad2,
        const float* __restrict__ as3, const float* __restrict__ ad3,
        const float* __restrict__ b1, const float* __restrict__ b2,
        const float* __restrict__ b3,
        const float* __restrict__ ln_w, const float* __restrict__ ln_b,
        float* __restrict__ out, int E, int N) {
    __shared__ float ys[48];
    int tl = threadIdx.x;
    int pl = tl >> 3;
    int q  = tl & 7;
    int id = blockIdx.x * 48 + pl;
    bool valid = id < 3 * N;
    int n = id / 3;
    int r = id - 3 * n;
    float denom = 0.f, acc = 0.f;
    if (valid) {
        float a_s = ((r == 0) ? as1 : (r == 1) ? as2 : as3)[0];
        float a_d = ((r == 0) ? ad1 : (r == 1) ? ad2 : ad3)[0];
        int s0 = start[(size_t)r * N + n];
        int d  = deg[(size_t)r * N + n];
        float hd = h2[id];
        float sd = a_d * hd;
        const unsigned short* cs = csr + (size_t)r * E + s0;
        for (int i = q; i < d; i += 8) {
            float hs = h2[(size_t)cs[i] * 3 + r];
            float e2 = __expf(lrelu(fmaf(a_s, hs, sd)));
            denom += e2;
            acc = fmaf(e2, hs, acc);
        }
        if (q == 0) {
            float ev = __expf(lrelu(fmaf(a_s, hd, sd)));
            denom += ev;
            acc = fmaf(ev, hd, acc);
        }
    }
    denom += __shfl_xor(denom, 1); denom += __shfl_xor(denom, 2); denom += __shfl_xor(denom, 4);
    acc   += __shfl_xor(acc, 1);   acc   += __shfl_xor(acc, 2);   acc   += __shfl_xor(acc, 4);
    if (valid && q == 0) {
        float b = ((r == 0) ? b1 : (r == 1) ? b2 : b3)[0];
        ys[pl] = (acc / (denom + 1e-16f) + b) * ln_w[r];
    }
    __syncthreads();
    if (valid && q == 0 && r == 0)
        out[n] = ys[pl] + ys[pl + 1] + ys[pl + 2] + ln_b[0];
}

extern "C" void kernel_launch(void* const* d_in, const int* in_sizes, int n_in,
                              void* d_out, int out_size, void* d_ws, size_t ws_size,
                              hipStream_t stream) {
    const float* X  = (const float*)d_in[0];
    const int*   A1 = (const int*)d_in[1];
    const int*   A2 = (const int*)d_in[2];
    const int*   A3 = (const int*)d_in[3];
    const float* W11 = (const float*)d_in[5];
    const float* as11 = (const float*)d_in[6];
    const float* ad11 = (const float*)d_in[7];
    const float* b11 = (const float*)d_in[8];
    const float* W12 = (const float*)d_in[9];
    const float* as12 = (const float*)d_in[10];
    const float* ad12 = (const float*)d_in[11];
    const float* b12 = (const float*)d_in[12];
    const float* W21 = (const float*)d_in[13];
    const float* as21 = (const float*)d_in[14];
    const float* ad21 = (const float*)d_in[15];
    const float* b21 = (const float*)d_in[16];
    const float* W22 = (const float*)d_in[17];
    const float* as22 = (const float*)d_in[18];
    const float* ad22 = (const float*)d_in[19];
    const float* b22 = (const float*)d_in[20];
    const float* W31 = (const float*)d_in[21];
    const float* as31 = (const float*)d_in[22];
    const float* ad31 = (const float*)d_in[23];
    const float* b31 = (const float*)d_in[24];
    const float* W32 = (const float*)d_in[25];
    const float* as32 = (const float*)d_in[26];
    const float* ad32 = (const float*)d_in[27];
    const float* b32 = (const float*)d_in[28];
    const float* ln_w = (const float*)d_in[29];
    const float* ln_b = (const float*)d_in[30];

    const int N = in_sizes[0] / 64;
    const int E = in_sizes[1] / 2;
    const int NB  = (N + 127) >> 7;          // dst buckets (<=512)
    const int nbP = (E + EPB - 1) / EPB;     // scatter blocks per branch
    const int nL1 = (N + L1_NODES - 1) / L1_NODES;

    // workspace layout
    float* w = (float*)d_ws;
    float* s_src1 = w; w += (size_t)N * 24;
    float* s_dst1 = w; w += (size_t)N * 24;
    float* h2     = w; w += (size_t)N * 3;
    unsigned short* h_bf = (unsigned short*)w; w += (size_t)N * 192;  // N*384 bf16
    int* iw     = (int*)w;
    int* deg    = iw; iw += (size_t)3 * N;
    int* start  = iw; iw += (size_t)3 * N;
    int* bktcnt = iw; iw += (size_t)3 * NB;
    int* gstart = iw; iw += (size_t)3 * NB;
    uint32_t* ebuf = (uint32_t*)iw; iw += (size_t)3 * NB * CAP;
    unsigned short* csr = (unsigned short*)iw;

    hipMemsetAsync(bktcnt, 0, (size_t)3 * NB * sizeof(int), stream);

    // ---- fused: linear1 ∥ slab scatter (single edge pass; zero per-edge global atomics) ----
    k_sc_lin1<<<nL1 + 3 * nbP, 384, 0, stream>>>(
        X, W11, W21, W31, as11, ad11, as21, ad21, as31, ad31,
        h_bf, s_src1, s_dst1,
        A1, A2, A3, bktcnt, ebuf, h2, nL1, nbP, NB, E, N);

    k_scan<<<1, 512, 0, stream>>>(bktcnt, gstart, NB);
    k_p4<<<dim3(NB, 3), 512, 0, stream>>>(ebuf, gstart, bktcnt, csr, deg, start, NB, E, N);

    // ---- layer-1 aggregation (+ fused layer-2 linear) ----
    {
        dim3 grid(N, 3);
        k_agg1<<<grid, 64, 0, stream>>>(h_bf, s_src1, s_dst1, deg, start, csr,
                                        b11, b21, b31, W12, W22, W32, h2, E, N);
    }

    // ---- layer-2 aggregation + final projection ----
    {
        int nb = (3 * N + 47) / 48;
        k_agg2f<<<nb, 384, 0, stream>>>(
            h2, deg, start, csr,
            as12, ad12, as22, ad22, as32, ad32,
            b12, b22, b32, ln_w, ln_b, (float*)d_out, E, N);
    }
}